// Round 8
// baseline (194.502 us; speedup 1.0000x reference)
//
#include <hip/hip_runtime.h>
#include <hip/hip_bf16.h>
#include <stdint.h>

#define B_N   16384
#define L_N   63
#define K2LOG2E 2.8853900817779268f   // 2*log2(e)
#define LOG2E   1.4426950408889634f

typedef unsigned int   u32;
typedef unsigned short u16;
typedef __attribute__((ext_vector_type(8))) __bf16 bf16x8;
typedef __attribute__((ext_vector_type(4))) float  f32x4;

__device__ __forceinline__ u16 f2b(float f){
  u32 u = __builtin_bit_cast(u32, f);
  u += 0x7fffu + ((u >> 16) & 1u);
  return (u16)(u >> 16);
}
__device__ __forceinline__ u32 pk_bf16(float lo, float hi){
  u32 r;
  asm("v_cvt_pk_bf16_f32 %0, %1, %2" : "=v"(r) : "v"(lo), "v"(hi));
  return r;
}
// tanh(a): 3 VALU + 2 trans, saturation-safe
__device__ __forceinline__ float tanh_pre(float a){
  float t = __builtin_amdgcn_exp2f(a * K2LOG2E);
  float r = __builtin_amdgcn_rcpf(t + 1.0f);
  return fmaf(-2.0f, r, 1.0f);
}
// tanh(acc + b) with bb pre-scaled by K2LOG2E
__device__ __forceinline__ float tanh_b(float acc, float bb){
  float t = __builtin_amdgcn_exp2f(fmaf(acc, K2LOG2E, bb));
  float r = __builtin_amdgcn_rcpf(t + 1.0f);
  return fmaf(-2.0f, r, 1.0f);
}

// ---- merged weight conversion (one block per layer l) ----
// W1[l][d][n] (masked d<=l) -> w1t[l][n][64], col63 = b1  (x col63 = 1)
// W2[l][h][n]               -> w2t[l][n][128]   (transpose)
__global__ void k_conv_w(const float* __restrict__ W1, const float* __restrict__ b1,
                         const float* __restrict__ W2,
                         u16* __restrict__ w1t, u16* __restrict__ w2t){
  __shared__ u16 t[16384];
  const int l = blockIdx.x, tid = threadIdx.x;
  #pragma unroll
  for (int i = 0; i < 32; ++i) t[i*256 + tid] = 0;
  __syncthreads();
  for (int i = 0; i < 32; ++i){
    int idx = i*256 + tid;              // idx = d*128 + n (coalesced)
    if (idx < 63*128){
      int d = idx >> 7, n = idx & 127;
      if (d <= l) t[n*64 + d] = f2b(W1[(l*63 + d)*128 + n]);
    }
  }
  if (tid < 128) t[tid*64 + 63] = f2b(b1[l*128 + tid]);
  __syncthreads();
  {
    uint4* o = (uint4*)(w1t + l*(128*64));
    const uint4* s4 = (const uint4*)t;
    #pragma unroll
    for (int i = 0; i < 4; ++i) o[i*256 + tid] = s4[i*256 + tid];
  }
  __syncthreads();
  #pragma unroll
  for (int i = 0; i < 64; ++i){
    int idx = i*256 + tid;              // idx = h*128 + n (coalesced)
    int h = idx >> 7, n = idx & 127;
    t[n*128 + h] = f2b(W2[l*16384 + idx]);
  }
  __syncthreads();
  {
    uint4* o = (uint4*)(w2t + l*(128*128));
    const uint4* s4 = (const uint4*)t;
    #pragma unroll
    for (int i = 0; i < 8; ++i) o[i*256 + tid] = s4[i*256 + tid];
  }
}

// ---- x f32 -> bf16, col63 := 1.0 (bias lane for stage 1) ----
__global__ void k_conv_x(const float* __restrict__ x, u16* __restrict__ out){
  int idx = blockIdx.x*256 + threadIdx.x;
  float4 v = ((const float4*)x)[idx];
  ushort4 r;
  r.x = f2b(v.x); r.y = f2b(v.y); r.z = f2b(v.z);
  r.w = ((idx & 15) == 15) ? (u16)0x3F80 : f2b(v.w);
  ((ushort4*)out)[idx] = r;
}

// ---- main: block = 512 threads = 8 waves, 128 batch rows x layer l.
// Wave (hg,bg): hg=wv&3 owns h-rows [32hg,32hg+32), bg=wv>>2 owns batch rows
// [64bg,64bg+64). Same LDS as R5 (36.8KB) but per 512 threads -> 4 blocks/CU
// = 32 waves/CU (100% cap). Per-wave state ~half of R5 -> fits 64 VGPR.
__global__ __launch_bounds__(512, 8)
void k_main(const u16* __restrict__ W1T, const u16* __restrict__ W2T,
            const u16* __restrict__ xbf, const float* __restrict__ x,
            const float* __restrict__ b2, const float* __restrict__ W3,
            const float* __restrict__ b3,
            float* __restrict__ out, float* __restrict__ alph)
{
  __shared__ __align__(16) char lds[36864];   // h1 32KB | sc 4KB
  const int tid = threadIdx.x;
  const int l  = blockIdx.y;
  const int bx = blockIdx.x;
  const int wv = tid >> 6;
  const int ln = tid & 63;
  const int c  = ln & 15;
  const int g  = ln >> 4;
  const int hg = wv & 3;               // h-row group (32 rows)
  const int bg = wv >> 2;              // batch group (64 rows)
  const int rowbase = bx*128;
  const int sx = (c & 7) << 4;         // row-swizzle XOR ((brow&7)==(c&7))
  char*   const h1b = lds;
  float2* const sc  = (float2*)(lds + 32768);   // [hg][brow 0..127]

  const u16* w1p = W1T + l*(128*64);
  const u16* w2p = W2T + l*(128*128);

  // ---- stage 1: h1T[h][b] = tanh(W1T . xT)  (b1 in col 63, x col63 = 1) ----
  bf16x8 a1f[2][2];
  #pragma unroll
  for (int m = 0; m < 2; ++m)
    #pragma unroll
    for (int s = 0; s < 2; ++s)
      a1f[m][s] = *(const bf16x8*)(w1p + (hg*32 + m*16 + c)*64 + s*32 + g*8);

  f32x4 acc[2][4] = {};
  #pragma unroll
  for (int s = 0; s < 2; ++s)
    #pragma unroll
    for (int bt = 0; bt < 4; ++bt){
      bf16x8 xf = *(const bf16x8*)(xbf + (size_t)(rowbase + bg*64 + bt*16 + c)*64 + s*32 + g*8);
      acc[0][bt] = __builtin_amdgcn_mfma_f32_16x16x32_bf16(a1f[0][s], xf, acc[0][bt], 0,0,0);
      acc[1][bt] = __builtin_amdgcn_mfma_f32_16x16x32_bf16(a1f[1][s], xf, acc[1][bt], 0,0,0);
    }

  // epilogue 1: tanh, pack, swizzled 8B store into h1[brow][h]
  #pragma unroll
  for (int m = 0; m < 2; ++m){
    int h0 = hg*32 + m*16 + g*4;
    #pragma unroll
    for (int bt = 0; bt < 4; ++bt){
      u32 p0 = pk_bf16(tanh_pre(acc[m][bt][0]), tanh_pre(acc[m][bt][1]));
      u32 p1 = pk_bf16(tanh_pre(acc[m][bt][2]), tanh_pre(acc[m][bt][3]));
      int brow = bg*64 + bt*16 + c;
      *(uint2*)(h1b + brow*256 + ((h0*2) ^ sx)) = make_uint2(p0, p1);
    }
  }
  __syncthreads();

  // ---- stage 2: h2T[n][b] = W2T . h1T ----
  f32x4 acc2[2][4] = {};
  #pragma unroll
  for (int s = 0; s < 4; ++s){
    bf16x8 a0 = *(const bf16x8*)(w2p + (hg*32 +  0 + c)*128 + s*32 + g*8);
    bf16x8 a1 = *(const bf16x8*)(w2p + (hg*32 + 16 + c)*128 + s*32 + g*8);
    #pragma unroll
    for (int bt = 0; bt < 4; ++bt){
      int brow = bg*64 + bt*16 + c;
      bf16x8 hf = *(const bf16x8*)(h1b + brow*256 + ((s*64 + g*16) ^ sx));
      acc2[0][bt] = __builtin_amdgcn_mfma_f32_16x16x32_bf16(a0, hf, acc2[0][bt], 0,0,0);
      acc2[1][bt] = __builtin_amdgcn_mfma_f32_16x16x32_bf16(a1, hf, acc2[1][bt], 0,0,0);
    }
  }

  // epilogue 2 + stage 3: tanh(acc2+b2), dot W3, per-wave partials
  float part[4][2] = {};
  #pragma unroll
  for (int m = 0; m < 2; ++m){
    int q = hg*8 + m*4 + g;                      // row-quad index n0/4
    float4 bbv = ((const float4*)(b2 + l*128))[q];
    float4 w3a = ((const float4*)(W3 + l*256))[q*2 + 0];
    float4 w3b = ((const float4*)(W3 + l*256))[q*2 + 1];
    float bb[4]  = { bbv.x*K2LOG2E, bbv.y*K2LOG2E, bbv.z*K2LOG2E, bbv.w*K2LOG2E };
    float w30[4] = { w3a.x, w3a.z, w3b.x, w3b.z };
    float w31[4] = { w3a.y, w3a.w, w3b.y, w3b.w };
    #pragma unroll
    for (int bt = 0; bt < 4; ++bt)
      #pragma unroll
      for (int r = 0; r < 4; ++r){
        float h2 = tanh_b(acc2[m][bt][r], bb[r]);
        part[bt][0] = fmaf(h2, w30[r], part[bt][0]);
        part[bt][1] = fmaf(h2, w31[r], part[bt][1]);
      }
  }
  #pragma unroll
  for (int bt = 0; bt < 4; ++bt)
    #pragma unroll
    for (int o = 0; o < 2; ++o){
      float v = part[bt][o];
      v += __shfl_xor(v, 16, 64);
      v += __shfl_xor(v, 32, 64);
      part[bt][o] = v;
    }
  if (g == 0){
    #pragma unroll
    for (int bt = 0; bt < 4; ++bt)
      sc[hg*128 + bg*64 + bt*16 + c] = make_float2(part[bt][0], part[bt][1]);
  }
  __syncthreads();

  // tail: finish mu/alpha, fuse z-store (reversed), save alpha for logdet
  if (tid < 128){
    int row = rowbase + tid;
    float2 s0 = sc[tid], s1 = sc[128+tid], s2 = sc[256+tid], s3 = sc[384+tid];
    float muv = s0.x + s1.x + s2.x + s3.x + b3[l*2 + 0];
    float alv = s0.y + s1.y + s2.y + s3.y + b3[l*2 + 1];
    float xv  = x[(size_t)row*64 + l + 1];
    out[(size_t)row*64 + 62 - l] = (xv - muv) * __builtin_amdgcn_exp2f(-alv * LOG2E);
    alph[(size_t)row*64 + l + 1] = alv;
  }
}

// ---- finalize: z column 63 (d=0 term) + logdet row-reduce ----
__global__ void k_fin(const float* __restrict__ x, const float* __restrict__ alph,
                      const float* __restrict__ ip, float* __restrict__ out)
{
  int row = blockIdx.x*4 + (threadIdx.x >> 6);
  int d   = threadIdx.x & 63;
  float a = (d == 0) ? ip[1] : alph[(size_t)row*64 + d];
  float s = a;
  #pragma unroll
  for (int off = 32; off; off >>= 1) s += __shfl_xor(s, off, 64);
  if (d == 0){
    out[(size_t)row*64 + 63] = (x[(size_t)row*64] - ip[0]) * __builtin_amdgcn_exp2f(-a * LOG2E);
    out[(size_t)B_N*64 + row] = -s;
  }
}

extern "C" void kernel_launch(void* const* d_in, const int* in_sizes, int n_in,
                              void* d_out, int out_size, void* d_ws, size_t ws_size,
                              hipStream_t stream)
{
  const float* x  = (const float*)d_in[0];
  const float* W1 = (const float*)d_in[1];
  const float* b1 = (const float*)d_in[2];
  const float* W2 = (const float*)d_in[3];
  const float* b2 = (const float*)d_in[4];
  const float* W3 = (const float*)d_in[5];
  const float* b3 = (const float*)d_in[6];
  const float* ip = (const float*)d_in[7];

  char* ws = (char*)d_ws;
  // w1t 1MB | w2t 2MB | xbf 2MB | alpha 4MB = 9MB
  u16*   w1t  = (u16*)(ws);
  u16*   w2t  = (u16*)(ws + 1048576);
  u16*   xbf  = (u16*)(ws + 3145728);
  float* alph = (float*)(ws + 5242880);
  if (ws_size < 9437184) return;  // fail visibly rather than corrupt

  k_conv_w<<<L_N, 256, 0, stream>>>(W1, b1, W2, w1t, w2t);
  k_conv_x<<<(B_N*64/4)/256, 256, 0, stream>>>(x, xbf);

  dim3 grid(B_N/128, L_N);
  k_main<<<grid, 512, 0, stream>>>(w1t, w2t, xbf, x, b2, W3, b3,
                                   (float*)d_out, alph);

  k_fin<<<B_N/4, 256, 0, stream>>>(x, alph, ip, (float*)d_out);
}

// Round 9
// 149.863 us; speedup vs baseline: 1.2979x; 1.2979x over previous
//
#include <hip/hip_runtime.h>
#include <hip/hip_bf16.h>
#include <stdint.h>

#define B_N   16384
#define L_N   63
#define K2LOG2E 2.8853900817779268f   // 2*log2(e)
#define LOG2E   1.4426950408889634f

typedef unsigned int   u32;
typedef unsigned short u16;
typedef __attribute__((ext_vector_type(8))) __bf16 bf16x8;
typedef __attribute__((ext_vector_type(4))) float  f32x4;

__device__ __forceinline__ u16 f2b(float f){
  u32 u = __builtin_bit_cast(u32, f);
  u += 0x7fffu + ((u >> 16) & 1u);
  return (u16)(u >> 16);
}
__device__ __forceinline__ u32 pk_bf16(float lo, float hi){
  u32 r;
  asm("v_cvt_pk_bf16_f32 %0, %1, %2" : "=v"(r) : "v"(lo), "v"(hi));
  return r;
}
// tanh where the 2*log2(e) factor is PRE-BAKED into the weights:
// acc = 2log2e*(Wx+b) -> tanh = 1 - 2/(exp2(acc)+1). 2 VALU + 2 trans.
__device__ __forceinline__ float tanh_sc(float acc){
  float t = __builtin_amdgcn_exp2f(acc);
  float r = __builtin_amdgcn_rcpf(t + 1.0f);
  return fmaf(-2.0f, r, 1.0f);
}

// ---- W1[l][d][n] (masked d<=l) -> w1t[l][n][64] * K2LOG2E, col63 = b1*K ----
__global__ void k_conv_w1(const float* __restrict__ W1, const float* __restrict__ b1,
                          u16* __restrict__ out){
  __shared__ u16 t[128*64];
  const int l = blockIdx.x, tid = threadIdx.x;
  #pragma unroll
  for (int i = 0; i < 32; ++i) t[i*256 + tid] = 0;
  __syncthreads();
  for (int i = 0; i < 32; ++i){
    int idx = i*256 + tid;              // idx = d*128 + n (coalesced)
    if (idx < 63*128){
      int d = idx >> 7, n = idx & 127;
      if (d <= l) t[n*64 + d] = f2b(W1[(l*63 + d)*128 + n] * K2LOG2E);
    }
  }
  if (tid < 128) t[tid*64 + 63] = f2b(b1[l*128 + tid] * K2LOG2E);
  __syncthreads();
  uint4* o = (uint4*)(out + l*(128*64));
  const uint4* s4 = (const uint4*)t;
  #pragma unroll
  for (int i = 0; i < 4; ++i) o[i*256 + tid] = s4[i*256 + tid];
}

// ---- W2[l][h][n] -> w2t[l][n][160] * K2LOG2E: k0..127 = W2^T, k128 = b2, 0 pad ----
__global__ void k_conv_w2(const float* __restrict__ W2, const float* __restrict__ b2,
                          u16* __restrict__ out){
  __shared__ u16 t[128*160];
  const int l = blockIdx.x, tid = threadIdx.x;
  #pragma unroll
  for (int i = 0; i < 80; ++i) t[i*256 + tid] = 0;
  __syncthreads();
  #pragma unroll
  for (int i = 0; i < 64; ++i){
    int idx = i*256 + tid;              // idx = h*128 + n (coalesced)
    int h = idx >> 7, n = idx & 127;
    t[n*160 + h] = f2b(W2[l*16384 + idx] * K2LOG2E);
  }
  if (tid < 128) t[tid*160 + 128] = f2b(b2[l*128 + tid] * K2LOG2E);
  __syncthreads();
  uint4* o = (uint4*)(out + l*(128*160));
  const uint4* s4 = (const uint4*)t;
  #pragma unroll
  for (int i = 0; i < 10; ++i) o[i*256 + tid] = s4[i*256 + tid];
}

// ---- W3[l][n][2] -> w3t[l][16][128]: rows 0,1 = W3^T (unscaled), rest 0 ----
__global__ void k_conv_w3(const float* __restrict__ W3, u16* __restrict__ out){
  __shared__ u16 t[16*128];
  const int l = blockIdx.x, tid = threadIdx.x;
  #pragma unroll
  for (int i = 0; i < 8; ++i) t[i*256 + tid] = 0;
  __syncthreads();
  if (tid < 128){
    t[tid]       = f2b(W3[l*256 + tid*2 + 0]);
    t[128 + tid] = f2b(W3[l*256 + tid*2 + 1]);
  }
  __syncthreads();
  uint4* o = (uint4*)(out + l*(16*128));
  o[tid] = ((const uint4*)t)[tid];
}

// ---- x f32 -> bf16, col63 := 1.0 (bias lane for stage 1) ----
__global__ void k_conv_x(const float* __restrict__ x, u16* __restrict__ out){
  int idx = blockIdx.x*256 + threadIdx.x;
  float4 v = ((const float4*)x)[idx];
  ushort4 r;
  r.x = f2b(v.x); r.y = f2b(v.y); r.z = f2b(v.z);
  r.w = ((idx & 15) == 15) ? (u16)0x3F80 : f2b(v.w);
  ((ushort4*)out)[idx] = r;
}

// ---- main: R5 geometry (128 rows x layer, 4 waves own h-row M-tiles),
// but: weights pre-scaled by 2log2e, b2 via K=160 MFMA slice, stage-3 via
// MFMA on reused h1 buffer. LDS 32KB, 3 barriers, no atomics.
__global__ __launch_bounds__(256, 4)
void k_main(const u16* __restrict__ W1T, const u16* __restrict__ W2T,
            const u16* __restrict__ W3T, const u16* __restrict__ xbf,
            const float* __restrict__ x, const float* __restrict__ b3,
            float* __restrict__ out, float* __restrict__ alph)
{
  __shared__ __align__(16) char h1b[128*256];   // h1 then h2, [b][h] swizzled
  const int tid = threadIdx.x;
  const int l  = blockIdx.y;
  const int bx = blockIdx.x;
  const int wv = tid >> 6;
  const int ln = tid & 63;
  const int c  = ln & 15;
  const int g  = ln >> 4;
  const int rowbase = bx*128;
  const int sx = (c & 7) << 4;         // row-swizzle XOR ((b&7)==(c&7))

  const u16* w1p = W1T + l*(128*64);
  const u16* w2p = W2T + l*(128*160);
  const u16* w3p = W3T + l*(16*128);

  // ---- stage 1: h1T[h][b] = tanh(K*(W1T.xT))  (b1 in col 63, x col63=1) ----
  bf16x8 a1f[2][2];
  #pragma unroll
  for (int m = 0; m < 2; ++m)
    #pragma unroll
    for (int s = 0; s < 2; ++s)
      a1f[m][s] = *(const bf16x8*)(w1p + ((2*wv+m)*16 + c)*64 + s*32 + g*8);

  f32x4 acc[2][8] = {};
  #pragma unroll
  for (int s = 0; s < 2; ++s)
    #pragma unroll
    for (int bt = 0; bt < 8; ++bt){
      bf16x8 xf = *(const bf16x8*)(xbf + (size_t)(rowbase + bt*16 + c)*64 + s*32 + g*8);
      acc[0][bt] = __builtin_amdgcn_mfma_f32_16x16x32_bf16(a1f[0][s], xf, acc[0][bt], 0,0,0);
      acc[1][bt] = __builtin_amdgcn_mfma_f32_16x16x32_bf16(a1f[1][s], xf, acc[1][bt], 0,0,0);
    }

  // epilogue 1: tanh, pack, swizzled 8B store into h1[b][h]
  #pragma unroll
  for (int m = 0; m < 2; ++m){
    int h0 = (2*wv+m)*16 + g*4;
    #pragma unroll
    for (int bt = 0; bt < 8; ++bt){
      u32 p0 = pk_bf16(tanh_sc(acc[m][bt][0]), tanh_sc(acc[m][bt][1]));
      u32 p1 = pk_bf16(tanh_sc(acc[m][bt][2]), tanh_sc(acc[m][bt][3]));
      int b = bt*16 + c;
      *(uint2*)(h1b + b*256 + ((h0*2) ^ sx)) = make_uint2(p0, p1);
    }
  }
  __syncthreads();

  // ---- stage 2: acc2 = K*(W2T.h1T + b2), bias via k=128 slice + e0 frag ----
  uint4 cw; cw.x = (g == 0) ? 0x00003F80u : 0u; cw.y = cw.z = cw.w = 0u;
  bf16x8 cf = __builtin_bit_cast(bf16x8, cw);

  f32x4 acc2[2][8] = {};
  #pragma unroll
  for (int s = 0; s < 4; ++s){
    bf16x8 a0 = *(const bf16x8*)(w2p + ((2*wv+0)*16 + c)*160 + s*32 + g*8);
    bf16x8 a1 = *(const bf16x8*)(w2p + ((2*wv+1)*16 + c)*160 + s*32 + g*8);
    #pragma unroll
    for (int bt = 0; bt < 8; ++bt){
      int b = bt*16 + c;
      bf16x8 hf = *(const bf16x8*)(h1b + b*256 + ((s*64 + g*16) ^ sx));
      acc2[0][bt] = __builtin_amdgcn_mfma_f32_16x16x32_bf16(a0, hf, acc2[0][bt], 0,0,0);
      acc2[1][bt] = __builtin_amdgcn_mfma_f32_16x16x32_bf16(a1, hf, acc2[1][bt], 0,0,0);
    }
  }
  {
    bf16x8 ab0 = *(const bf16x8*)(w2p + ((2*wv+0)*16 + c)*160 + 128 + g*8);
    bf16x8 ab1 = *(const bf16x8*)(w2p + ((2*wv+1)*16 + c)*160 + 128 + g*8);
    #pragma unroll
    for (int bt = 0; bt < 8; ++bt){
      acc2[0][bt] = __builtin_amdgcn_mfma_f32_16x16x32_bf16(ab0, cf, acc2[0][bt], 0,0,0);
      acc2[1][bt] = __builtin_amdgcn_mfma_f32_16x16x32_bf16(ab1, cf, acc2[1][bt], 0,0,0);
    }
  }

  // epilogue 2: tanh, pack into regs; then barrier-fenced rewrite into h1b
  uint2 u2h[2][8];
  #pragma unroll
  for (int m = 0; m < 2; ++m)
    #pragma unroll
    for (int bt = 0; bt < 8; ++bt){
      u32 p0 = pk_bf16(tanh_sc(acc2[m][bt][0]), tanh_sc(acc2[m][bt][1]));
      u32 p1 = pk_bf16(tanh_sc(acc2[m][bt][2]), tanh_sc(acc2[m][bt][3]));
      u2h[m][bt] = make_uint2(p0, p1);
    }
  __syncthreads();          // all h1 reads complete before overwrite
  #pragma unroll
  for (int m = 0; m < 2; ++m){
    int n0 = (2*wv+m)*16 + g*4;
    #pragma unroll
    for (int bt = 0; bt < 8; ++bt){
      int b = bt*16 + c;
      *(uint2*)(h1b + b*256 + ((n0*2) ^ sx)) = u2h[m][bt];
    }
  }
  __syncthreads();          // h2 visible to all waves

  // ---- stage 3: [mu;alpha][16b] = W3T . h2T, wave owns batch tiles 2wv,2wv+1 ----
  bf16x8 a3[4];
  #pragma unroll
  for (int s = 0; s < 4; ++s)
    a3[s] = *(const bf16x8*)(w3p + c*128 + s*32 + g*8);

  f32x4 acc3[2] = {};
  #pragma unroll
  for (int bt = 0; bt < 2; ++bt){
    int b = (2*wv + bt)*16 + c;
    #pragma unroll
    for (int s = 0; s < 4; ++s){
      bf16x8 hb = *(const bf16x8*)(h1b + b*256 + ((s*64 + g*16) ^ sx));
      acc3[bt] = __builtin_amdgcn_mfma_f32_16x16x32_bf16(a3[s], hb, acc3[bt], 0,0,0);
    }
  }

  // tail: rows 0 (mu) / 1 (alpha) of D live in g==0 lanes, regs r=0/1
  if (g == 0){
    float b30 = b3[l*2 + 0], b31 = b3[l*2 + 1];
    #pragma unroll
    for (int bt = 0; bt < 2; ++bt){
      int row = rowbase + (2*wv + bt)*16 + c;
      float muv = acc3[bt][0] + b30;
      float alv = acc3[bt][1] + b31;
      float xv  = x[(size_t)row*64 + l + 1];
      out[(size_t)row*64 + 62 - l] = (xv - muv) * __builtin_amdgcn_exp2f(-alv * LOG2E);
      alph[(size_t)row*64 + l + 1] = alv;
    }
  }
}

// ---- finalize: z column 63 (d=0 term) + logdet row-reduce ----
__global__ void k_fin(const float* __restrict__ x, const float* __restrict__ alph,
                      const float* __restrict__ ip, float* __restrict__ out)
{
  int row = blockIdx.x*4 + (threadIdx.x >> 6);
  int d   = threadIdx.x & 63;
  float a = (d == 0) ? ip[1] : alph[(size_t)row*64 + d];
  float s = a;
  #pragma unroll
  for (int off = 32; off; off >>= 1) s += __shfl_xor(s, off, 64);
  if (d == 0){
    out[(size_t)row*64 + 63] = (x[(size_t)row*64] - ip[0]) * __builtin_amdgcn_exp2f(-a * LOG2E);
    out[(size_t)B_N*64 + row] = -s;
  }
}

extern "C" void kernel_launch(void* const* d_in, const int* in_sizes, int n_in,
                              void* d_out, int out_size, void* d_ws, size_t ws_size,
                              hipStream_t stream)
{
  const float* x  = (const float*)d_in[0];
  const float* W1 = (const float*)d_in[1];
  const float* b1 = (const float*)d_in[2];
  const float* W2 = (const float*)d_in[3];
  const float* b2 = (const float*)d_in[4];
  const float* W3 = (const float*)d_in[5];
  const float* b3 = (const float*)d_in[6];
  const float* ip = (const float*)d_in[7];

  char* ws = (char*)d_ws;
  // w1t 1.0MB | w2t 2.58MB @1MB | w3t 0.25MB @3.5MB | xbf 2MB @3.75MB | alph 4MB
  u16*   w1t  = (u16*)(ws);
  u16*   w2t  = (u16*)(ws + 1048576);
  u16*   w3t  = (u16*)(ws + 3670016);
  u16*   xbf  = (u16*)(ws + 3932160);
  float* alph = (float*)(ws + 6029312);
  if (ws_size < 10223616) return;  // fail visibly rather than corrupt

  k_conv_w1<<<L_N, 256, 0, stream>>>(W1, b1, w1t);
  k_conv_w2<<<L_N, 256, 0, stream>>>(W2, b2, w2t);
  k_conv_w3<<<L_N, 256, 0, stream>>>(W3, w3t);
  k_conv_x<<<(B_N*64/4)/256, 256, 0, stream>>>(x, xbf);

  dim3 grid(B_N/128, L_N);
  k_main<<<grid, 256, 0, stream>>>(w1t, w2t, w3t, xbf, x, b3,
                                   (float*)d_out, alph);

  k_fin<<<B_N/4, 256, 0, stream>>>(x, alph, ip, (float*)d_out);
}

// Round 10
// 148.491 us; speedup vs baseline: 1.3099x; 1.0092x over previous
//
#include <hip/hip_runtime.h>
#include <hip/hip_bf16.h>
#include <stdint.h>

#define B_N   16384
#define L_N   63
#define K2LOG2E 2.8853900817779268f   // 2*log2(e)
#define LOG2E   1.4426950408889634f

typedef unsigned int   u32;
typedef unsigned short u16;
typedef __attribute__((ext_vector_type(8))) __bf16 bf16x8;
typedef __attribute__((ext_vector_type(4))) float  f32x4;

__device__ __forceinline__ u16 f2b(float f){
  u32 u = __builtin_bit_cast(u32, f);
  u += 0x7fffu + ((u >> 16) & 1u);
  return (u16)(u >> 16);
}
__device__ __forceinline__ u32 pk_bf16(float lo, float hi){
  u32 r;
  asm("v_cvt_pk_bf16_f32 %0, %1, %2" : "=v"(r) : "v"(lo), "v"(hi));
  return r;
}
// tanh with 2*log2(e) pre-baked into weights: acc = 2log2e*(Wx+b)
// tanh = 1 - 2/(exp2(acc)+1). 2 VALU + 2 trans.
__device__ __forceinline__ float tanh_sc(float acc){
  float t = __builtin_amdgcn_exp2f(acc);
  float r = __builtin_amdgcn_rcpf(t + 1.0f);
  return fmaf(-2.0f, r, 1.0f);
}

// ---- W1[l][d][n] (masked d<=l) -> w1t[l][n][64] * K2LOG2E, col63 = b1*K ----
__global__ void k_conv_w1(const float* __restrict__ W1, const float* __restrict__ b1,
                          u16* __restrict__ out){
  __shared__ u16 t[128*64];
  const int l = blockIdx.x, tid = threadIdx.x;
  #pragma unroll
  for (int i = 0; i < 32; ++i) t[i*256 + tid] = 0;
  __syncthreads();
  for (int i = 0; i < 32; ++i){
    int idx = i*256 + tid;              // idx = d*128 + n (coalesced)
    if (idx < 63*128){
      int d = idx >> 7, n = idx & 127;
      if (d <= l) t[n*64 + d] = f2b(W1[(l*63 + d)*128 + n] * K2LOG2E);
    }
  }
  if (tid < 128) t[tid*64 + 63] = f2b(b1[l*128 + tid] * K2LOG2E);
  __syncthreads();
  uint4* o = (uint4*)(out + l*(128*64));
  const uint4* s4 = (const uint4*)t;
  #pragma unroll
  for (int i = 0; i < 4; ++i) o[i*256 + tid] = s4[i*256 + tid];
}

// ---- W2[l][h][n] -> w2t[l][n][160] * K2LOG2E: k0..127 = W2^T, k128 = b2 ----
__global__ void k_conv_w2(const float* __restrict__ W2, const float* __restrict__ b2,
                          u16* __restrict__ out){
  __shared__ u16 t[128*160];
  const int l = blockIdx.x, tid = threadIdx.x;
  #pragma unroll
  for (int i = 0; i < 80; ++i) t[i*256 + tid] = 0;
  __syncthreads();
  #pragma unroll
  for (int i = 0; i < 64; ++i){
    int idx = i*256 + tid;              // idx = h*128 + n (coalesced)
    int h = idx >> 7, n = idx & 127;
    t[n*160 + h] = f2b(W2[l*16384 + idx] * K2LOG2E);
  }
  if (tid < 128) t[tid*160 + 128] = f2b(b2[l*128 + tid] * K2LOG2E);
  __syncthreads();
  uint4* o = (uint4*)(out + l*(128*160));
  const uint4* s4 = (const uint4*)t;
  #pragma unroll
  for (int i = 0; i < 10; ++i) o[i*256 + tid] = s4[i*256 + tid];
}

// ---- x f32 -> bf16, col63 := 1.0 (bias lane for stage 1) ----
__global__ void k_conv_x(const float* __restrict__ x, u16* __restrict__ out){
  int idx = blockIdx.x*256 + threadIdx.x;
  float4 v = ((const float4*)x)[idx];
  ushort4 r;
  r.x = f2b(v.x); r.y = f2b(v.y); r.z = f2b(v.z);
  r.w = ((idx & 15) == 15) ? (u16)0x3F80 : f2b(v.w);
  ((ushort4*)out)[idx] = r;
}

// ---- main: TWO layers per block (lA=ly, lB=ly+32), 64 batch rows, 4 waves
// own h-row M-tiles [32wv,32wv+32) for BOTH layers. Two independent
// dependency chains per wave fill each other's stalls; x-fragments shared.
// 2 barriers, stage-3 = VALU dot (no h2 LDS round-trip), no atomics.
__global__ __launch_bounds__(256, 4)
void k_main(const u16* __restrict__ W1T, const u16* __restrict__ W2T,
            const u16* __restrict__ xbf, const float* __restrict__ x,
            const float* __restrict__ W3, const float* __restrict__ b3,
            float* __restrict__ out, float* __restrict__ alph)
{
  __shared__ __align__(16) char h1b[2*16384];   // [layer][64 rows][256B] swizzled
  __shared__ float2 sc[4][2][64];               // [wave][layer][row], 4KB
  const int tid = threadIdx.x;
  const int ly = blockIdx.y;
  const int bx = blockIdx.x;
  const int wv = tid >> 6;
  const int ln = tid & 63;
  const int c  = ln & 15;
  const int g  = ln >> 4;
  const bool hasB = (ly + 32 < L_N);
  const int rowbase = bx*64;
  const int sx = (c & 7) << 4;         // row-swizzle XOR ((b&7)==(c&7))

  // x fragments: shared by both layers' stage 1 (b1 rides in col 63, x63=1)
  bf16x8 xf[4][2];
  #pragma unroll
  for (int bt = 0; bt < 4; ++bt)
    #pragma unroll
    for (int s = 0; s < 2; ++s)
      xf[bt][s] = *(const bf16x8*)(xbf + (size_t)(rowbase + bt*16 + c)*64 + s*32 + g*8);

  // ---- stage 1, both layers: h1T[h][b] = tanh(K*(W1T.xT)) ----
  #pragma unroll
  for (int li = 0; li < 2; ++li){
    if (li == 0 || hasB){
      const int l = ly + li*32;
      const u16* w1p = W1T + l*(128*64);
      char* const hb = h1b + li*16384;
      bf16x8 a0[2], a1[2];
      #pragma unroll
      for (int m = 0; m < 2; ++m){
        const u16* ap = w1p + ((2*wv+m)*16 + c)*64 + g*8;
        a0[m] = *(const bf16x8*)(ap);
        a1[m] = *(const bf16x8*)(ap + 32);
      }
      f32x4 acc[2][4] = {};
      #pragma unroll
      for (int m = 0; m < 2; ++m)
        #pragma unroll
        for (int bt = 0; bt < 4; ++bt){
          acc[m][bt] = __builtin_amdgcn_mfma_f32_16x16x32_bf16(a0[m], xf[bt][0], acc[m][bt], 0,0,0);
          acc[m][bt] = __builtin_amdgcn_mfma_f32_16x16x32_bf16(a1[m], xf[bt][1], acc[m][bt], 0,0,0);
        }
      #pragma unroll
      for (int m = 0; m < 2; ++m){
        int h0 = (2*wv+m)*16 + g*4;
        #pragma unroll
        for (int bt = 0; bt < 4; ++bt){
          u32 p0 = pk_bf16(tanh_sc(acc[m][bt][0]), tanh_sc(acc[m][bt][1]));
          u32 p1 = pk_bf16(tanh_sc(acc[m][bt][2]), tanh_sc(acc[m][bt][3]));
          int b = bt*16 + c;
          *(uint2*)(hb + b*256 + ((h0*2) ^ sx)) = make_uint2(p0, p1);
        }
      }
    }
  }
  __syncthreads();

  // ---- stage 2 + 3, both layers: acc2 = K*(W2T.h1T + b2); tanh; W3 dot ----
  uint4 cw; cw.x = (g == 0) ? 0x00003F80u : 0u; cw.y = cw.z = cw.w = 0u;
  const bf16x8 cf = __builtin_bit_cast(bf16x8, cw);

  float part[2][4][2] = {};
  #pragma unroll
  for (int li = 0; li < 2; ++li){
    if (li == 0 || hasB){
      const int l = ly + li*32;
      const u16* w2p = W2T + l*(128*160);
      const char* const hb = h1b + li*16384;
      f32x4 acc2[2][4] = {};
      #pragma unroll
      for (int s = 0; s < 4; ++s){
        bf16x8 a0 = *(const bf16x8*)(w2p + ((2*wv+0)*16 + c)*160 + s*32 + g*8);
        bf16x8 a1 = *(const bf16x8*)(w2p + ((2*wv+1)*16 + c)*160 + s*32 + g*8);
        #pragma unroll
        for (int bt = 0; bt < 4; ++bt){
          int b = bt*16 + c;
          bf16x8 hf = *(const bf16x8*)(hb + b*256 + ((s*64 + g*16) ^ sx));
          acc2[0][bt] = __builtin_amdgcn_mfma_f32_16x16x32_bf16(a0, hf, acc2[0][bt], 0,0,0);
          acc2[1][bt] = __builtin_amdgcn_mfma_f32_16x16x32_bf16(a1, hf, acc2[1][bt], 0,0,0);
        }
      }
      {
        bf16x8 ab0 = *(const bf16x8*)(w2p + ((2*wv+0)*16 + c)*160 + 128 + g*8);
        bf16x8 ab1 = *(const bf16x8*)(w2p + ((2*wv+1)*16 + c)*160 + 128 + g*8);
        #pragma unroll
        for (int bt = 0; bt < 4; ++bt){
          acc2[0][bt] = __builtin_amdgcn_mfma_f32_16x16x32_bf16(ab0, cf, acc2[0][bt], 0,0,0);
          acc2[1][bt] = __builtin_amdgcn_mfma_f32_16x16x32_bf16(ab1, cf, acc2[1][bt], 0,0,0);
        }
      }
      // epilogue: tanh + W3 dot (regs only)
      #pragma unroll
      for (int m = 0; m < 2; ++m){
        int q = (2*wv+m)*4 + g;                  // row-quad index n0/4
        float4 w3a = ((const float4*)(W3 + l*256))[q*2 + 0];
        float4 w3b = ((const float4*)(W3 + l*256))[q*2 + 1];
        float w30[4] = { w3a.x, w3a.z, w3b.x, w3b.z };
        float w31[4] = { w3a.y, w3a.w, w3b.y, w3b.w };
        #pragma unroll
        for (int bt = 0; bt < 4; ++bt)
          #pragma unroll
          for (int r = 0; r < 4; ++r){
            float h2 = tanh_sc(acc2[m][bt][r]);
            part[li][bt][0] = fmaf(h2, w30[r], part[li][bt][0]);
            part[li][bt][1] = fmaf(h2, w31[r], part[li][bt][1]);
          }
      }
    }
  }

  // reduce the 4 g-groups, stash per-wave partials
  #pragma unroll
  for (int li = 0; li < 2; ++li)
    #pragma unroll
    for (int bt = 0; bt < 4; ++bt)
      #pragma unroll
      for (int o = 0; o < 2; ++o){
        float v = part[li][bt][o];
        v += __shfl_xor(v, 16, 64);
        v += __shfl_xor(v, 32, 64);
        part[li][bt][o] = v;
      }
  if (g == 0){
    #pragma unroll
    for (int li = 0; li < 2; ++li)
      #pragma unroll
      for (int bt = 0; bt < 4; ++bt)
        sc[wv][li][bt*16 + c] = make_float2(part[li][bt][0], part[li][bt][1]);
  }
  __syncthreads();

  // tail: 128 threads = 2 layers x 64 rows; fuse z-store, save alpha
  if (tid < 128){
    int li = tid >> 6, r = tid & 63;
    if (li == 0 || hasB){
      int l = ly + li*32;
      int row = rowbase + r;
      float2 s0 = sc[0][li][r], s1 = sc[1][li][r], s2 = sc[2][li][r], s3 = sc[3][li][r];
      float muv = s0.x + s1.x + s2.x + s3.x + b3[l*2 + 0];
      float alv = s0.y + s1.y + s2.y + s3.y + b3[l*2 + 1];
      float xv  = x[(size_t)row*64 + l + 1];
      out[(size_t)row*64 + 62 - l] = (xv - muv) * __builtin_amdgcn_exp2f(-alv * LOG2E);
      alph[(size_t)row*64 + l + 1] = alv;
    }
  }
}

// ---- finalize: z column 63 (d=0 term) + logdet row-reduce ----
__global__ void k_fin(const float* __restrict__ x, const float* __restrict__ alph,
                      const float* __restrict__ ip, float* __restrict__ out)
{
  int row = blockIdx.x*4 + (threadIdx.x >> 6);
  int d   = threadIdx.x & 63;
  float a = (d == 0) ? ip[1] : alph[(size_t)row*64 + d];
  float s = a;
  #pragma unroll
  for (int off = 32; off; off >>= 1) s += __shfl_xor(s, off, 64);
  if (d == 0){
    out[(size_t)row*64 + 63] = (x[(size_t)row*64] - ip[0]) * __builtin_amdgcn_exp2f(-a * LOG2E);
    out[(size_t)B_N*64 + row] = -s;
  }
}

extern "C" void kernel_launch(void* const* d_in, const int* in_sizes, int n_in,
                              void* d_out, int out_size, void* d_ws, size_t ws_size,
                              hipStream_t stream)
{
  const float* x  = (const float*)d_in[0];
  const float* W1 = (const float*)d_in[1];
  const float* b1 = (const float*)d_in[2];
  const float* W2 = (const float*)d_in[3];
  const float* b2 = (const float*)d_in[4];
  const float* W3 = (const float*)d_in[5];
  const float* b3 = (const float*)d_in[6];
  const float* ip = (const float*)d_in[7];

  char* ws = (char*)d_ws;
  // w1t 1.0MB@0 | w2t 2.46MB@1MB | xbf 2MB@3.5MB | alph 4MB@5.5MB
  u16*   w1t  = (u16*)(ws);
  u16*   w2t  = (u16*)(ws + 1048576);
  u16*   xbf  = (u16*)(ws + 3670016);
  float* alph = (float*)(ws + 5767168);
  if (ws_size < 9961472) return;  // fail visibly rather than corrupt

  k_conv_w1<<<L_N, 256, 0, stream>>>(W1, b1, w1t);
  k_conv_w2<<<L_N, 256, 0, stream>>>(W2, b2, w2t);
  k_conv_x<<<(B_N*64/4)/256, 256, 0, stream>>>(x, xbf);

  dim3 grid(B_N/64, 32);
  k_main<<<grid, 256, 0, stream>>>(w1t, w2t, xbf, x, W3, b3,
                                   (float*)d_out, alph);

  k_fin<<<B_N/4, 256, 0, stream>>>(x, alph, ip, (float*)d_out);
}